// Round 3
// baseline (430.420 us; speedup 1.0000x reference)
//
#include <hip/hip_runtime.h>
#include <math.h>

// ThrusterLag: y[k] = a*y[k-1] + (1-a)*tanh(2*deadzone((u-7.5)/2.5)), y[-1]=u_nl[0]
// a = exp(-DT/tau), tau = softplus(tau_param) + TAU_MIN, per channel.
// Shapes: u_seq (512, 8192, 8) f32; tau_param (8,) f32; out (512, 8192, 8) f32.
//
// 3-pass chunked linear scan (constant coefficient => carries compose in closed
// form: a^KSEG = exp(-KSEG*DT/tau)).
//   passA: per (b,seg) thread, local scan value with zero carry-in (all 8 ch).
//   passB: per (b,c) thread, serial scan over segment summaries -> carries,
//          written IN-PLACE over the summary buffer (buf[s] := carry_in[s+1]).
//   passC: per (b,seg) thread, seed with carry (s==0: recompute u_nl(u[b,0,:])),
//          recompute nonlinearity, emit y with nontemporal stores.

typedef float v4f __attribute__((ext_vector_type(4)));  // native vec for NT stores

constexpr int kB = 512;
constexpr int kL = 8192;
constexpr int kC = 8;

constexpr float kDT     = 0.01f;
constexpr float kTauMin = 0.01f;

__device__ __forceinline__ float softplus_f(float p) {
    return fmaxf(p, 0.0f) + log1pf(__expf(-fabsf(p)));
}

// nonlinearity: tanh(2 * deadzone((u - 7.5)/2.5))
__device__ __forceinline__ float u_nl(float u) {
    float uu = (u - 7.5f) * 0.4f;
    float ud = copysignf(fmaxf(fabsf(uu) - 0.05f, 0.0f), uu);
    // tanh(2*ud) = (e^{4*ud} - 1)/(e^{4*ud} + 1); 4*ud in [-7.6, 7.6]
    float e = __expf(4.0f * ud);
    return (e - 1.0f) * __builtin_amdgcn_rcpf(e + 1.0f);
}

__device__ __forceinline__ void load_coeffs(const float* __restrict__ tp,
                                            float* a, float* oma) {
    #pragma unroll
    for (int c = 0; c < kC; ++c) {
        float tau = softplus_f(tp[c]) + kTauMin;
        a[c]   = __expf(-kDT / tau);
        oma[c] = 1.0f - a[c];
    }
}

// ---------------- Pass A ----------------
template <int KSEG>
__global__ __launch_bounds__(256) void passA(const float* __restrict__ u,
                                             const float* __restrict__ tp,
                                             float* __restrict__ buf) {
    constexpr int NSEG = kL / KSEG;
    int t = blockIdx.x * 256 + threadIdx.x;   // [0, kB*NSEG)
    int b = t / NSEG;
    int s = t % NSEG;

    float a[kC], oma[kC], acc[kC];
    load_coeffs(tp, a, oma);
    #pragma unroll
    for (int c = 0; c < kC; ++c) acc[c] = 0.0f;

    const v4f* src = (const v4f*)(u + ((size_t)b * kL + (size_t)s * KSEG) * kC);
    #pragma unroll
    for (int i = 0; i < KSEG; ++i) {
        v4f x0 = src[2 * i];
        v4f x1 = src[2 * i + 1];
        float v[kC] = {x0.x, x0.y, x0.z, x0.w, x1.x, x1.y, x1.z, x1.w};
        #pragma unroll
        for (int c = 0; c < kC; ++c)
            acc[c] = a[c] * acc[c] + oma[c] * u_nl(v[c]);
    }

    v4f* lb = (v4f*)(buf + (size_t)t * kC);
    lb[0] = (v4f){acc[0], acc[1], acc[2], acc[3]};
    lb[1] = (v4f){acc[4], acc[5], acc[6], acc[7]};
}

// ---------------- Pass B (in-place: buf[s] := carry_in[s+1]) ----------------
template <int KSEG>
__global__ __launch_bounds__(256) void passB(const float* __restrict__ u,
                                             const float* __restrict__ tp,
                                             float* __restrict__ buf) {
    constexpr int NSEG = kL / KSEG;
    int t = blockIdx.x * 256 + threadIdx.x;   // [0, kB*kC)
    int b = t >> 3;
    int c = t & (kC - 1);

    float tau = softplus_f(tp[c]) + kTauMin;
    float A = __expf(-kDT * (float)KSEG / tau);   // a^KSEG

    float carry = u_nl(u[(size_t)b * kL * kC + c]);   // carry_in[0] = u_nl[b,0,c]

    #pragma unroll 8
    for (int s = 0; s < NSEG - 1; ++s) {
        size_t idx = ((size_t)b * NSEG + s) * kC + c;
        carry = A * carry + buf[idx];   // carry_in[s+1]
        buf[idx] = carry;               // passC seg s+1 reads buf[s]
    }
}

// ---------------- Pass C ----------------
template <int KSEG>
__global__ __launch_bounds__(256) void passC(const float* __restrict__ u,
                                             const float* __restrict__ tp,
                                             const float* __restrict__ buf,
                                             float* __restrict__ out) {
    constexpr int NSEG = kL / KSEG;
    int t = blockIdx.x * 256 + threadIdx.x;   // [0, kB*NSEG)
    int b = t / NSEG;
    int s = t % NSEG;

    float a[kC], oma[kC], y[kC];
    load_coeffs(tp, a, oma);

    size_t off = ((size_t)b * kL + (size_t)s * KSEG) * kC;

    if (s == 0) {
        const v4f* q = (const v4f*)(u + (size_t)b * kL * kC);
        v4f q0 = q[0], q1 = q[1];
        y[0] = u_nl(q0.x); y[1] = u_nl(q0.y); y[2] = u_nl(q0.z); y[3] = u_nl(q0.w);
        y[4] = u_nl(q1.x); y[5] = u_nl(q1.y); y[6] = u_nl(q1.z); y[7] = u_nl(q1.w);
    } else {
        const v4f* cb = (const v4f*)(buf + ((size_t)b * NSEG + s - 1) * kC);
        v4f c0 = cb[0], c1 = cb[1];
        y[0] = c0.x; y[1] = c0.y; y[2] = c0.z; y[3] = c0.w;
        y[4] = c1.x; y[5] = c1.y; y[6] = c1.z; y[7] = c1.w;
    }

    const v4f* src = (const v4f*)(u + off);
    v4f*       dst = (v4f*)(out + off);

    #pragma unroll
    for (int i = 0; i < KSEG; ++i) {
        v4f x0 = src[2 * i];
        v4f x1 = src[2 * i + 1];
        float v[kC] = {x0.x, x0.y, x0.z, x0.w, x1.x, x1.y, x1.z, x1.w};
        #pragma unroll
        for (int c = 0; c < kC; ++c)
            y[c] = a[c] * y[c] + oma[c] * u_nl(v[c]);
        __builtin_nontemporal_store((v4f){y[0], y[1], y[2], y[3]}, &dst[2 * i]);
        __builtin_nontemporal_store((v4f){y[4], y[5], y[6], y[7]}, &dst[2 * i + 1]);
    }
}

template <int KSEG>
static void run_all(const float* u, const float* tp, float* buf, float* out,
                    hipStream_t stream) {
    constexpr int NSEG = kL / KSEG;
    passA<KSEG><<<(kB * NSEG) / 256, 256, 0, stream>>>(u, tp, buf);
    passB<KSEG><<<(kB * kC) / 256, 256, 0, stream>>>(u, tp, buf);
    passC<KSEG><<<(kB * NSEG) / 256, 256, 0, stream>>>(u, tp, buf, out);
}

extern "C" void kernel_launch(void* const* d_in, const int* in_sizes, int n_in,
                              void* d_out, int out_size, void* d_ws, size_t ws_size,
                              hipStream_t stream) {
    const float* u  = (const float*)d_in[0];
    const float* tp = (const float*)d_in[1];
    float* out = (float*)d_out;
    float* buf = (float*)d_ws;

    // KSEG=16 needs kB*(kL/16)*kC*4 = 8 MB of workspace; fall back if ws is small.
    if (ws_size >= (size_t)kB * (kL / 16) * kC * 4) {
        run_all<16>(u, tp, buf, out, stream);
    } else {
        run_all<64>(u, tp, buf, out, stream);
    }
}

// Round 4
// 136.265 us; speedup vs baseline: 3.1587x; 3.1587x over previous
//
#include <hip/hip_runtime.h>
#include <math.h>

// ThrusterLag: y[k] = a*y[k-1] + (1-a)*tanh(2*deadzone((u-7.5)/2.5)), y[-1]=u_nl[0]
// a = exp(-DT/tau), tau = softplus(tau_param) + TAU_MIN, per channel.
// Shapes: u_seq (512, 8192, 8) f32; tau_param (8,) f32; out (512, 8192, 8) f32.
//
// 3-pass chunked linear scan. Key layout fact: global thread gt (one segment of
// KSEG steps, all 8 channels) owns floats [gt*KSEG*8, (gt+1)*KSEG*8) — fully
// contiguous. passC stages stores through LDS so (a) every HBM write is a full
// 64B line and (b) global stores don't sit in the vmcnt queue throttling the
// read pipeline (R3 lesson: NT partial-line stores = 2x write amplification).

typedef float v4f __attribute__((ext_vector_type(4)));

constexpr int kB = 512;
constexpr int kL = 8192;
constexpr int kC = 8;

constexpr float kDT     = 0.01f;
constexpr float kTauMin = 0.01f;

__device__ __forceinline__ float softplus_f(float p) {
    return fmaxf(p, 0.0f) + log1pf(__expf(-fabsf(p)));
}

// nonlinearity: tanh(2 * deadzone((u - 7.5)/2.5))
__device__ __forceinline__ float u_nl(float u) {
    float uu = (u - 7.5f) * 0.4f;
    float ud = copysignf(fmaxf(fabsf(uu) - 0.05f, 0.0f), uu);
    // tanh(2*ud) = (e^{4*ud} - 1)/(e^{4*ud} + 1); 4*ud in [-7.6, 7.6]
    float e = __expf(4.0f * ud);
    return (e - 1.0f) * __builtin_amdgcn_rcpf(e + 1.0f);
}

__device__ __forceinline__ void load_coeffs(const float* __restrict__ tp,
                                            float* a, float* oma) {
    #pragma unroll
    for (int c = 0; c < kC; ++c) {
        float tau = softplus_f(tp[c]) + kTauMin;
        a[c]   = __expf(-kDT / tau);
        oma[c] = 1.0f - a[c];
    }
}

// ---------------- Pass A: per-segment local scan (zero carry-in) ----------------
template <int KSEG>
__global__ __launch_bounds__(256) void passA(const float* __restrict__ u,
                                             const float* __restrict__ tp,
                                             float* __restrict__ buf) {
    constexpr int NSEG = kL / KSEG;
    int gt = blockIdx.x * 256 + threadIdx.x;   // [0, kB*NSEG)

    float a[kC], oma[kC], acc[kC];
    load_coeffs(tp, a, oma);
    #pragma unroll
    for (int c = 0; c < kC; ++c) acc[c] = 0.0f;

    const v4f* src = (const v4f*)(u + (size_t)gt * KSEG * kC);
    #pragma unroll
    for (int i = 0; i < KSEG; ++i) {
        v4f x0 = src[2 * i];
        v4f x1 = src[2 * i + 1];
        float v[kC] = {x0.x, x0.y, x0.z, x0.w, x1.x, x1.y, x1.z, x1.w};
        #pragma unroll
        for (int c = 0; c < kC; ++c)
            acc[c] = a[c] * acc[c] + oma[c] * u_nl(v[c]);
    }

    v4f* lb = (v4f*)(buf + (size_t)gt * kC);
    lb[0] = (v4f){acc[0], acc[1], acc[2], acc[3]};
    lb[1] = (v4f){acc[4], acc[5], acc[6], acc[7]};
}

// ------- Pass B: per (b,c) serial scan over summaries (in-place carries) -------
template <int KSEG>
__global__ __launch_bounds__(256) void passB(const float* __restrict__ u,
                                             const float* __restrict__ tp,
                                             float* __restrict__ buf) {
    constexpr int NSEG = kL / KSEG;
    int t = blockIdx.x * 256 + threadIdx.x;   // [0, kB*kC)
    int b = t >> 3;
    int c = t & (kC - 1);

    float tau = softplus_f(tp[c]) + kTauMin;
    float A = __expf(-kDT * (float)KSEG / tau);   // a^KSEG

    float carry = u_nl(u[(size_t)b * kL * kC + c]);   // carry_in[0] = u_nl[b,0,c]

    #pragma unroll 8
    for (int s = 0; s < NSEG - 1; ++s) {
        size_t idx = ((size_t)b * NSEG + s) * kC + c;
        carry = A * carry + buf[idx];   // carry_in[s+1]
        buf[idx] = carry;               // passC seg s+1 reads buf[s]
    }
}

// ------- Pass C: recompute with carry seed; stores staged through LDS -------
template <int KSEG>
__global__ __launch_bounds__(256) void passC(const float* __restrict__ u,
                                             const float* __restrict__ tp,
                                             const float* __restrict__ buf,
                                             float* __restrict__ out) {
    constexpr int NSEG = kL / KSEG;
    constexpr int CH   = 4;            // steps computed per chunk
    constexpr int NCH  = KSEG / CH;    // chunks per segment
    __shared__ v4f lds[2 * CH][256];   // [slot j][producer thread t] = 32 KB

    int t  = threadIdx.x;
    int gt = blockIdx.x * 256 + t;
    int b  = gt / NSEG;
    int s  = gt % NSEG;

    float a[kC], oma[kC], y[kC];
    load_coeffs(tp, a, oma);

    if (s == 0) {
        const v4f* q = (const v4f*)(u + (size_t)b * kL * kC);
        v4f q0 = q[0], q1 = q[1];
        y[0] = u_nl(q0.x); y[1] = u_nl(q0.y); y[2] = u_nl(q0.z); y[3] = u_nl(q0.w);
        y[4] = u_nl(q1.x); y[5] = u_nl(q1.y); y[6] = u_nl(q1.z); y[7] = u_nl(q1.w);
    } else {
        const v4f* cb = (const v4f*)(buf + ((size_t)gt - 1) * kC);
        v4f c0 = cb[0], c1 = cb[1];
        y[0] = c0.x; y[1] = c0.y; y[2] = c0.z; y[3] = c0.w;
        y[4] = c1.x; y[5] = c1.y; y[6] = c1.z; y[7] = c1.w;
    }

    const v4f* src = (const v4f*)(u + (size_t)gt * KSEG * kC);
    // block's output region in v4f units (contiguous: gt -> gt*KSEG*2)
    size_t region = (size_t)blockIdx.x * 256 * (KSEG * 2);
    v4f* dst = (v4f*)out;

    const int q     = t & 7;   // float4-within-piece for flush
    const int pbase = t >> 3;  // piece group base

    for (int c = 0; c < NCH; ++c) {
        v4f res[2 * CH];
        #pragma unroll
        for (int i = 0; i < CH; ++i) {
            v4f x0 = src[(c * CH + i) * 2];
            v4f x1 = src[(c * CH + i) * 2 + 1];
            float v[kC] = {x0.x, x0.y, x0.z, x0.w, x1.x, x1.y, x1.z, x1.w};
            #pragma unroll
            for (int ch = 0; ch < kC; ++ch)
                y[ch] = a[ch] * y[ch] + oma[ch] * u_nl(v[ch]);
            res[2 * i]     = (v4f){y[0], y[1], y[2], y[3]};
            res[2 * i + 1] = (v4f){y[4], y[5], y[6], y[7]};
        }

        if (c) __syncthreads();          // previous flush must finish before overwrite
        #pragma unroll
        for (int j = 0; j < 2 * CH; ++j)
            lds[j][t] = res[j];          // lanes write consecutive 16B: conflict-free
        __syncthreads();

        // Flush: 8-lane groups emit one producer-thread's 128B piece per round
        // (full 64B lines to HBM). Piece p = thread p's chunk-c data.
        #pragma unroll
        for (int r = 0; r < 8; ++r) {
            int p = r * 32 + pbase;
            dst[region + (size_t)p * (KSEG * 2) + c * (2 * CH) + q] = lds[q][p];
        }
    }
}

template <int KSEG>
static void run_all(const float* u, const float* tp, float* buf, float* out,
                    hipStream_t stream) {
    constexpr int NSEG = kL / KSEG;
    passA<KSEG><<<(kB * NSEG) / 256, 256, 0, stream>>>(u, tp, buf);
    passB<KSEG><<<(kB * kC) / 256, 256, 0, stream>>>(u, tp, buf);
    passC<KSEG><<<(kB * NSEG) / 256, 256, 0, stream>>>(u, tp, buf, out);
}

extern "C" void kernel_launch(void* const* d_in, const int* in_sizes, int n_in,
                              void* d_out, int out_size, void* d_ws, size_t ws_size,
                              hipStream_t stream) {
    const float* u  = (const float*)d_in[0];
    const float* tp = (const float*)d_in[1];
    float* out = (float*)d_out;
    float* buf = (float*)d_ws;

    // KSEG=16 needs kB*(kL/16)*kC*4 = 8 MB of workspace; fall back if ws is small.
    if (ws_size >= (size_t)kB * (kL / 16) * kC * 4) {
        run_all<16>(u, tp, buf, out, stream);
    } else {
        run_all<64>(u, tp, buf, out, stream);
    }
}